// Round 7
// baseline (1104.909 us; speedup 1.0000x reference)
//
#include <hip/hip_runtime.h>

#define NB 512
#define NT 256
#define N_NODES 8192
#define N_EDGES 262144
#define NFEAT 200
#define NHID 128

struct Params {
    const float* x; const int* ei; const float* ew;
    const float* g0; const float* g1;
    const float* Wg1; const float* bg1; const float* ln1g; const float* ln1b;
    const float* Wg2; const float* bg2; const float* ln2g; const float* ln2b;
    const float* p0W; const float* p0b; const float* p1W; const float* p1b;
    const float* e0W; const float* e0b; const float* e1W; const float* e1b;
    const float* fcW; const float* fcb;
    float* out;
    float* bufA; float* bufB; float* bufC;
    int* c0; float* xc0; float* tbl;
    int* deg; float* A0;
    int* bar;                 // bar[0]=cnt, bar[1]=gen (zeroed by memset each call)
    int* row_start; int* cursor; int2* esort;
    float* partials;          // aliases bufA (dead after P3)
};

// generation grid barrier; all NB blocks co-resident (launch_bounds(256,2), 512<=2*256CU)
__device__ __forceinline__ void gbar(int* cnt, int* gen) {
    __syncthreads();
    if (threadIdx.x == 0) {
        int g = __hip_atomic_load(gen, __ATOMIC_RELAXED, __HIP_MEMORY_SCOPE_AGENT);
        int a = __hip_atomic_fetch_add(cnt, 1, __ATOMIC_ACQ_REL, __HIP_MEMORY_SCOPE_AGENT);
        if (a == NB - 1) {
            __hip_atomic_store(cnt, 0, __ATOMIC_RELAXED, __HIP_MEMORY_SCOPE_AGENT);
            __hip_atomic_store(gen, g + 1, __ATOMIC_RELEASE, __HIP_MEMORY_SCOPE_AGENT);
        } else {
            while (__hip_atomic_load(gen, __ATOMIC_ACQUIRE, __HIP_MEMORY_SCOPE_AGENT) == g)
                __builtin_amdgcn_s_sleep(2);
        }
    }
    __syncthreads();
}

// weighted CSR gather of one 128-dim row (2 dims per lane), 4-way unrolled
__device__ __forceinline__ float2 csr_gather(const int* __restrict__ row_start,
                                             const int2* __restrict__ esort,
                                             const float* __restrict__ H,
                                             int row, int lane) {
    int s0 = row_start[row], s1 = row_start[row + 1];
    float ax0 = 0.f, ay0 = 0.f, ax1 = 0.f, ay1 = 0.f;
    float ax2 = 0.f, ay2 = 0.f, ax3 = 0.f, ay3 = 0.f;
    int e = s0;
    for (; e + 3 < s1; e += 4) {
        int2 p0 = esort[e], p1 = esort[e + 1], p2 = esort[e + 2], p3 = esort[e + 3];
        float2 v0 = *(const float2*)(H + (size_t)p0.x * 128 + lane * 2);
        float2 v1 = *(const float2*)(H + (size_t)p1.x * 128 + lane * 2);
        float2 v2 = *(const float2*)(H + (size_t)p2.x * 128 + lane * 2);
        float2 v3 = *(const float2*)(H + (size_t)p3.x * 128 + lane * 2);
        float w0 = __int_as_float(p0.y), w1 = __int_as_float(p1.y);
        float w2 = __int_as_float(p2.y), w3 = __int_as_float(p3.y);
        ax0 += w0 * v0.x; ay0 += w0 * v0.y;
        ax1 += w1 * v1.x; ay1 += w1 * v1.y;
        ax2 += w2 * v2.x; ay2 += w2 * v2.y;
        ax3 += w3 * v3.x; ay3 += w3 * v3.y;
    }
    for (; e < s1; ++e) {
        int2 p0 = esort[e];
        float2 v0 = *(const float2*)(H + (size_t)p0.x * 128 + lane * 2);
        float w0 = __int_as_float(p0.y);
        ax0 += w0 * v0.x; ay0 += w0 * v0.y;
    }
    return make_float2((ax0 + ax1) + (ax2 + ax3), (ay0 + ay1) + (ay2 + ay3));
}

// bias + LayerNorm + relu on a wave-held row (2 dims/lane)
__device__ __forceinline__ float2 ln_relu(float vx, float vy, int lane,
                                          const float* __restrict__ bias,
                                          const float* __restrict__ g,
                                          const float* __restrict__ b) {
    float2 bs = *(const float2*)(bias + lane * 2);
    vx += bs.x; vy += bs.y;
    float s = vx + vy, ss = vx * vx + vy * vy;
    for (int off = 32; off; off >>= 1) {
        s += __shfl_xor(s, off, 64);
        ss += __shfl_xor(ss, off, 64);
    }
    float mu = s * (1.f / 128.f);
    float var = ss * (1.f / 128.f) - mu * mu;
    float rs = rsqrtf(var + 1e-5f);
    float2 gg = *(const float2*)(g + lane * 2);
    float2 bb = *(const float2*)(b + lane * 2);
    return make_float2(fmaxf((vx - mu) * rs * gg.x + bb.x, 0.f),
                       fmaxf((vy - mu) * rs * gg.y + bb.y, 0.f));
}

__global__ __launch_bounds__(256, 2) void mega(Params p) {
    __shared__ float smem[10752];     // 42 KB -> 2+ blocks/CU
    const int bid = blockIdx.x, tid = threadIdx.x;
    const int lane = tid & 63, wid = tid >> 6;

    // ================= P0: gemm1 (x @ Wg1^T -> bufA) + dst histogram =================
    {
        float* a_s = smem;                       // 16*200 = 3200 floats
        int row0 = bid * 16;
        const float* Ab = p.x + (size_t)row0 * NFEAT;
        for (int idx = tid; idx < 16 * NFEAT; idx += NT) a_s[idx] = Ab[idx];
        __syncthreads();
        int j = tid & 127, rh = tid >> 7;
        float acc[8] = {0.f, 0.f, 0.f, 0.f, 0.f, 0.f, 0.f, 0.f};
        const float4* W4 = (const float4*)(p.Wg1 + (size_t)j * NFEAT);
        for (int k4 = 0; k4 < NFEAT / 4; ++k4) {
            float4 w = W4[k4];
            int k = k4 * 4;
            #pragma unroll
            for (int r = 0; r < 8; ++r) {
                const float* ar = a_s + (rh * 8 + r) * NFEAT + k;
                acc[r] += ar[0] * w.x + ar[1] * w.y + ar[2] * w.z + ar[3] * w.w;
            }
        }
        #pragma unroll
        for (int r = 0; r < 8; ++r)
            p.bufA[(size_t)(row0 + rh * 8 + r) * 128 + j] = acc[r];
        const int* dst = p.ei + N_EDGES;
        for (int e = bid * NT + tid; e < N_EDGES; e += NB * NT)
            atomicAdd(&p.deg[dst[e]], 1);
    }
    gbar(p.bar, p.bar + 1);

    // ================= P1: prefix scan of deg -> row_start, cursor (block 0) ==========
    if (bid == 0) {
        int* part = (int*)smem;
        int base = tid * 32;
        int s = 0;
        for (int i = 0; i < 32; ++i) s += p.deg[base + i];
        part[tid] = s;
        __syncthreads();
        for (int off = 1; off < 256; off <<= 1) {
            int v = (tid >= off) ? part[tid - off] : 0;
            __syncthreads();
            part[tid] += v;
            __syncthreads();
        }
        int run = part[tid] - s;                 // exclusive base of this 32-chunk
        for (int i = 0; i < 32; ++i) {
            int d = p.deg[base + i];
            p.row_start[base + i] = run;
            p.cursor[base + i] = run;
            run += d;
        }
        if (tid == 255) p.row_start[N_NODES] = part[255];
    }
    gbar(p.bar, p.bar + 1);

    // ================= P2: scatter edges into dst-sorted (src, w) ====================
    for (int e = bid * NT + tid; e < N_EDGES; e += NB * NT) {
        int d = p.ei[N_EDGES + e];
        int pos = atomicAdd(&p.cursor[d], 1);
        p.esort[pos] = make_int2(p.ei[e], __float_as_int(p.ew[e]));
    }
    gbar(p.bar, p.bar + 1);

    // ================= P3: agg1 + LN + relu, fused gemm2 in LDS -> bufC ==============
    {
        float* rows = smem;                       // 16*128 = 2048
        float* Wst  = smem + 2048;                // 64 rows * 132 (pad) = 8448
        int base = bid * 16;
        for (int rr = 0; rr < 4; ++rr) {
            int r16 = rr * 4 + wid;
            float2 a = csr_gather(p.row_start, p.esort, p.bufA, base + r16, lane);
            float2 y = ln_relu(a.x, a.y, lane, p.bg1, p.ln1g, p.ln1b);
            rows[r16 * 128 + lane * 2] = y.x;
            rows[r16 * 128 + lane * 2 + 1] = y.y;
        }
        __syncthreads();
        for (int half = 0; half < 2; ++half) {
            const float* Wsrc = p.Wg2 + (size_t)half * 64 * 128;
            for (int idx = tid; idx < 8192; idx += NT)
                Wst[(idx >> 7) * 132 + (idx & 127)] = Wsrc[idx];
            __syncthreads();
            int j = tid & 63, rgrp = tid >> 6;
            const float4* wp = (const float4*)(Wst + j * 132);
            #pragma unroll
            for (int q = 0; q < 4; ++q) {
                int r16 = rgrp + q * 4;
                const float4* rp = (const float4*)(rows + r16 * 128);
                float acc = 0.f;
                for (int kk = 0; kk < 32; ++kk) {
                    float4 rv = rp[kk], wv = wp[kk];
                    acc += rv.x * wv.x + rv.y * wv.y + rv.z * wv.z + rv.w * wv.w;
                }
                p.bufC[(size_t)(base + r16) * 128 + half * 64 + j] = acc;
            }
            __syncthreads();
        }
    }
    gbar(p.bar, p.bar + 1);

    // ================= P4: agg2 + LN + relu -> latent(bufB), pool0 c0 + xc0 partials ==
    {
        float* Ws   = smem;                        // 1280
        float* accs = smem + 1280;                 // 1280
        float* bsh  = smem + 2560;                 // 10
        for (int i = tid; i < 1280; i += NT) { Ws[i] = p.p0W[i]; accs[i] = 0.f; }
        if (tid < 10) bsh[tid] = p.p0b[tid];
        __syncthreads();
        int base = bid * 16;
        for (int rr = 0; rr < 4; ++rr) {
            int row = base + rr * 4 + wid;
            float2 a = csr_gather(p.row_start, p.esort, p.bufC, row, lane);
            float2 y = ln_relu(a.x, a.y, lane, p.bg2, p.ln2g, p.ln2b);
            *(float2*)(p.bufB + (size_t)row * 128 + lane * 2) = y;
            float pk[10];
            #pragma unroll
            for (int k = 0; k < 10; ++k)
                pk[k] = y.x * Ws[k * 128 + lane * 2] + y.y * Ws[k * 128 + lane * 2 + 1];
            for (int off = 32; off; off >>= 1) {
                #pragma unroll
                for (int k = 0; k < 10; ++k) pk[k] += __shfl_xor(pk[k], off, 64);
            }
            const float* gr = p.g0 + (size_t)row * 10;
            int best = 0;
            float bv = pk[0] + bsh[0] + gr[0];
            #pragma unroll
            for (int k = 1; k < 10; ++k) {
                float z = pk[k] + bsh[k] + gr[k];
                if (z > bv) { bv = z; best = k; }   // first max wins (jnp.argmax)
            }
            if (lane == 0) p.c0[row] = best;
            atomicAdd(&accs[best * 128 + lane * 2], y.x);
            atomicAdd(&accs[best * 128 + lane * 2 + 1], y.y);
        }
        __syncthreads();
        for (int i = tid; i < 1280; i += NT)
            p.partials[(size_t)bid * 1280 + i] = accs[i];
    }
    gbar(p.bar, p.bar + 1);

    // ================= P5: A0 edge-pool (blocks<256) + xc0 reduce (256..265) =========
    if (bid < 256) {
        float* As = smem;
        for (int i = tid; i < 100; i += NT) As[i] = 0.f;
        __syncthreads();
        for (int e = bid * NT + tid; e < N_EDGES; e += 256 * NT) {
            int a = p.c0[p.ei[e]], b = p.c0[p.ei[N_EDGES + e]];
            atomicAdd(&As[a * 10 + b], p.ew[e]);
        }
        __syncthreads();
        for (int i = tid; i < 100; i += NT) atomicAdd(&p.A0[i], As[i]);
    } else if (bid < 266) {
        int k = bid - 256;
        int d = tid & 127, half = tid >> 7;
        float s0 = 0.f, s1 = 0.f, s2 = 0.f, s3 = 0.f;
        for (int b = half * 256; b < half * 256 + 256; b += 4) {
            s0 += p.partials[(size_t)(b    ) * 1280 + k * 128 + d];
            s1 += p.partials[(size_t)(b + 1) * 1280 + k * 128 + d];
            s2 += p.partials[(size_t)(b + 2) * 1280 + k * 128 + d];
            s3 += p.partials[(size_t)(b + 3) * 1280 + k * 128 + d];
        }
        float* sm = smem;
        sm[tid] = (s0 + s1) + (s2 + s3);
        __syncthreads();
        if (tid < 128) p.xc0[k * 128 + d] = sm[tid] + sm[tid + 128];
    }
    gbar(p.bar, p.bar + 1);

    // ================= P6: small solver (block 0) || out-GEMM (blocks 1..256) ========
    if (bid == 0) {
        float* xc0n = smem;
        float* adj0 = smem + 1280;
        float* m0   = smem + 1380;
        float* l1   = smem + 2660;
        float* xc1n = smem + 3940;
        float* l2   = smem + 4580;
        float* A1   = smem + 5220;
        int*   c1   = (int*)(smem + 5248);
        float* red  = smem + 5260;

        for (int r = wid; r < 10; r += 4) {
            float2 v = *(const float2*)(p.xc0 + r * 128 + lane * 2);
            float ss = v.x * v.x + v.y * v.y;
            for (int off = 32; off; off >>= 1) ss += __shfl_xor(ss, off, 64);
            float sc = 1.f / fmaxf(sqrtf(ss), 1e-12f);
            xc0n[r * 128 + lane * 2] = v.x * sc;
            xc0n[r * 128 + lane * 2 + 1] = v.y * sc;
        }
        __syncthreads();
        if (tid == 0) {
            float s = 0.f;
            for (int i = 0; i < 100; ++i) s += p.A0[i];
            red[0] = s + 1e-6f;
        }
        __syncthreads();
        if (tid < 100) adj0[tid] = p.A0[tid] / red[0];
        __syncthreads();
        for (int idx = tid; idx < 1280; idx += NT) {
            int r = idx >> 7, d = idx & 127;
            float acc = 0.f;
            #pragma unroll
            for (int a = 0; a < 10; ++a) acc += adj0[r * 10 + a] * xc0n[a * 128 + d];
            m0[idx] = acc;
        }
        __syncthreads();
        for (int idx = tid; idx < 1280; idx += NT) {
            int r = idx >> 7, d = idx & 127;
            float acc = p.e0b[d];
            const float* wrow = p.e0W + d * 128;
            for (int k = 0; k < 128; ++k) acc += m0[r * 128 + k] * wrow[k];
            l1[idx] = fmaxf(acc, 0.f);
        }
        __syncthreads();
        if (tid < 10) {
            int best = 0;
            float bv = -1e30f;
            for (int j = 0; j < 5; ++j) {
                float acc = p.p1b[j] + p.g1[tid * 5 + j];
                const float* wrow = p.p1W + j * 128;
                for (int k = 0; k < 128; ++k) acc += l1[tid * 128 + k] * wrow[k];
                if (acc > bv) { bv = acc; best = j; }
            }
            c1[tid] = best;
        }
        __syncthreads();
        for (int idx = tid; idx < 640; idx += NT) {
            int m = idx >> 7, d = idx & 127;
            float acc = 0.f;
            #pragma unroll
            for (int k = 0; k < 10; ++k)
                if (c1[k] == m) acc += l1[k * 128 + d];
            xc1n[idx] = acc;
        }
        __syncthreads();
        for (int r = wid; r < 5; r += 4) {
            float2 v = *(const float2*)(xc1n + r * 128 + lane * 2);
            float ss = v.x * v.x + v.y * v.y;
            for (int off = 32; off; off >>= 1) ss += __shfl_xor(ss, off, 64);
            float sc = 1.f / fmaxf(sqrtf(ss), 1e-12f);
            xc1n[r * 128 + lane * 2] = v.x * sc;
            xc1n[r * 128 + lane * 2 + 1] = v.y * sc;
        }
        __syncthreads();
        if (tid < 25) {
            int m = tid / 5, n = tid % 5;
            float acc = 0.f;
            for (int a = 0; a < 10; ++a)
                for (int b = 0; b < 10; ++b)
                    if (c1[a] == m && c1[b] == n) acc += adj0[a * 10 + b];
            A1[tid] = acc;
        }
        __syncthreads();
        if (tid == 0) {
            float s = 0.f;
            for (int i = 0; i < 25; ++i) s += A1[i];
            red[1] = s + 25e-8f;
        }
        __syncthreads();
        float den1 = red[1];
        for (int idx = tid; idx < 640; idx += NT) {
            int r = idx >> 7, d = idx & 127;
            float acc = 0.f;
            #pragma unroll
            for (int a = 0; a < 5; ++a) acc += A1[r * 5 + a] * xc1n[a * 128 + d];
            m0[idx] = acc / den1;
        }
        __syncthreads();
        for (int idx = tid; idx < 640; idx += NT) {
            int r = idx >> 7, d = idx & 127;
            float acc = p.e1b[d];
            const float* wrow = p.e1W + d * 128;
            for (int k = 0; k < 128; ++k) acc += m0[r * 128 + k] * wrow[k];
            l2[idx] = fmaxf(acc, 0.f);
        }
        __syncthreads();
        for (int idx = tid; idx < 160; idx += NT) {
            int k = idx >> 4, o = idx & 15;
            float acc = p.fcb[o];
            const float* fB = p.fcW + o * 384 + 128;
            const float* fC = p.fcW + o * 384 + 256;
            const float* a1 = l1 + k * 128;
            const float* a2 = l2 + c1[k] * 128;
            for (int d = 0; d < 128; ++d) acc += a1[d] * fB[d] + a2[d] * fC[d];
            p.tbl[idx] = acc;
        }
    } else if (bid <= 256) {
        // pacc[row][o] = latent[row] . fcW[o,0:128]   (tbl-independent part of out)
        float* fA = smem;                       // 2048
        for (int i = tid; i < 2048; i += NT)
            fA[i] = p.fcW[(i >> 7) * 384 + (i & 127)];
        __syncthreads();
        int sub = lane & 7;
        int row = (bid - 1) * 32 + wid * 8 + (lane >> 3);
        const float4* lp = (const float4*)(p.bufB + (size_t)row * 128 + sub * 16);
        float4 x0 = lp[0], x1 = lp[1], x2 = lp[2], x3 = lp[3];
        float pr[16];
        #pragma unroll
        for (int o = 0; o < 16; ++o) {
            const float4* fo = (const float4*)(fA + o * 128 + sub * 16);
            float4 w0 = fo[0], w1 = fo[1], w2 = fo[2], w3 = fo[3];
            float a = x0.x * w0.x + x0.y * w0.y + x0.z * w0.z + x0.w * w0.w;
            a += x1.x * w1.x + x1.y * w1.y + x1.z * w1.z + x1.w * w1.w;
            a += x2.x * w2.x + x2.y * w2.y + x2.z * w2.z + x2.w * w2.w;
            a += x3.x * w3.x + x3.y * w3.y + x3.z * w3.z + x3.w * w3.w;
            pr[o] = a;
        }
        #pragma unroll
        for (int off = 1; off < 8; off <<= 1) {
            #pragma unroll
            for (int o = 0; o < 16; ++o) pr[o] += __shfl_xor(pr[o], off, 64);
        }
        float2 r = make_float2(pr[2 * sub], pr[2 * sub + 1]);
        *(float2*)(p.bufC + (size_t)row * 16 + 2 * sub) = r;   // bufC reused as pacc
    }
    gbar(p.bar, p.bar + 1);

    // ================= P7: out = pacc + tbl[c0[row]] =================================
    {
        int i = bid * NT + tid;                  // NB*NT == 131072 == 8192*16 exactly
        int row = i >> 4, o = i & 15;
        p.out[i] = p.bufC[i] + p.tbl[p.c0[row] * 16 + o];
    }
}

extern "C" void kernel_launch(void* const* d_in, const int* in_sizes, int n_in,
                              void* d_out, int out_size, void* d_ws, size_t ws_size,
                              hipStream_t stream) {
    float* ws = (float*)d_ws;
    Params p;
    p.x    = (const float*)d_in[0];
    p.ei   = (const int*)d_in[1];
    p.ew   = (const float*)d_in[2];
    p.g0   = (const float*)d_in[3];
    p.g1   = (const float*)d_in[4];
    p.Wg1  = (const float*)d_in[5];
    p.bg1  = (const float*)d_in[6];
    p.ln1g = (const float*)d_in[7];
    p.ln1b = (const float*)d_in[8];
    p.Wg2  = (const float*)d_in[9];
    p.bg2  = (const float*)d_in[10];
    p.ln2g = (const float*)d_in[11];
    p.ln2b = (const float*)d_in[12];
    p.p0W  = (const float*)d_in[13];
    p.p0b  = (const float*)d_in[14];
    p.p1W  = (const float*)d_in[15];
    p.p1b  = (const float*)d_in[16];
    p.e0W  = (const float*)d_in[17];
    p.e0b  = (const float*)d_in[18];
    p.e1W  = (const float*)d_in[19];
    p.e1b  = (const float*)d_in[20];
    p.fcW  = (const float*)d_in[21];
    p.fcb  = (const float*)d_in[22];
    p.out  = (float*)d_out;

    p.bufA = ws;
    p.bufB = p.bufA + (size_t)N_NODES * 128;
    p.bufC = p.bufB + (size_t)N_NODES * 128;
    p.c0   = (int*)(p.bufC + (size_t)N_NODES * 128);
    p.xc0  = (float*)(p.c0 + N_NODES);
    p.tbl  = p.xc0 + 1280;
    p.deg  = (int*)(p.tbl + 160);                 // ---- memset range start
    p.A0   = (float*)(p.deg + N_NODES);
    p.bar  = (int*)(p.A0 + 100);                  // cnt, gen  ---- memset range end
    p.row_start = p.bar + 2;
    p.cursor    = p.row_start + N_NODES + 2;
    p.esort     = (int2*)(p.cursor + N_NODES);
    p.partials  = p.bufA;                          // bufA dead after P3

    // zero deg + A0 + barrier state in one fill
    hipMemsetAsync(p.deg, 0, (N_NODES + 100 + 2) * sizeof(int), stream);

    mega<<<NB, NT, 0, stream>>>(p);
}

// Round 8
// 207.941 us; speedup vs baseline: 5.3136x; 5.3136x over previous
//
#include <hip/hip_runtime.h>

#define N_NODES 8192
#define N_EDGES 262144
#define NFEAT 200
#define NHID 128

// ---------------- GEMM body: C[8 rows,128] = A[8,K] @ W[128,K]^T ----------------
template<int K>
__device__ __forceinline__ void gemm_body(const float* __restrict__ A,
                                          const float* __restrict__ W,
                                          float* __restrict__ C, int bid) {
    __shared__ float a_s[8 * K];
    int row0 = bid * 8;
    const float* Ab = A + (size_t)row0 * K;
    for (int idx = threadIdx.x; idx < 8 * K; idx += 128) a_s[idx] = Ab[idx];
    __syncthreads();
    int j = threadIdx.x;
    float acc[8] = {0.f, 0.f, 0.f, 0.f, 0.f, 0.f, 0.f, 0.f};
    const float4* W4 = (const float4*)(W + (size_t)j * K);
    for (int k4 = 0; k4 < K / 4; ++k4) {
        float4 w = W4[k4];
        int k = k4 * 4;
        #pragma unroll
        for (int r = 0; r < 8; ++r) {
            const float* ar = a_s + r * K + k;
            acc[r] += ar[0] * w.x + ar[1] * w.y + ar[2] * w.z + ar[3] * w.w;
        }
    }
    #pragma unroll
    for (int r = 0; r < 8; ++r) C[(size_t)(row0 + r) * 128 + j] = acc[r];
}

// fused: blocks [0,1024) gemm layer-1; blocks [1024,1088) histogram of dst
__global__ __launch_bounds__(128) void gemm1_hist(const float* __restrict__ A,
                                                  const float* __restrict__ W,
                                                  float* __restrict__ C,
                                                  const int* __restrict__ ei,
                                                  int* __restrict__ deg) {
    if (blockIdx.x < N_NODES / 8) {
        gemm_body<NFEAT>(A, W, C, blockIdx.x);
    } else {
        const int* dst = ei + N_EDGES;
        for (int e = (blockIdx.x - N_NODES / 8) * 128 + threadIdx.x; e < N_EDGES; e += 64 * 128)
            atomicAdd(&deg[dst[e]], 1);
    }
}

// single block, 256 threads: exclusive prefix sum of deg[8192] -> row_start, cursor
__global__ __launch_bounds__(256) void scan_kernel(const int* __restrict__ deg,
                                                   int* __restrict__ row_start,
                                                   int* __restrict__ cursor) {
    __shared__ int part[256];
    __shared__ int partx[257];
    int tid = threadIdx.x;
    int base = tid * 32;
    int s = 0;
    for (int i = 0; i < 32; ++i) s += deg[base + i];
    part[tid] = s;
    __syncthreads();
    if (tid == 0) {
        int run = 0;
        for (int i = 0; i < 256; ++i) { partx[i] = run; run += part[i]; }
        partx[256] = run;
    }
    __syncthreads();
    int run = partx[tid];
    for (int i = 0; i < 32; ++i) {
        row_start[base + i] = run;
        cursor[base + i] = run;
        run += deg[base + i];
    }
    if (tid == 255) row_start[N_NODES] = run;
}

// scatter edges into dst-sorted order, packed (src, weight-bits)
__global__ __launch_bounds__(256) void scatter_kernel(const int* __restrict__ ei,
                                                      const float* __restrict__ ew,
                                                      int* __restrict__ cursor,
                                                      int2* __restrict__ esort, int E) {
    int e = blockIdx.x * blockDim.x + threadIdx.x;
    if (e < E) {
        int d = ei[E + e];
        int pos = atomicAdd(&cursor[d], 1);
        esort[pos] = make_int2(ei[e], __float_as_int(ew[e]));
    }
}

// weighted CSR gather of one 128-dim row (2 dims per lane), 4-way unrolled
__device__ __forceinline__ float2 csr_gather(const int* __restrict__ row_start,
                                             const int2* __restrict__ esort,
                                             const float* __restrict__ H,
                                             int row, int lane) {
    int s0 = row_start[row], s1 = row_start[row + 1];
    float ax0 = 0.f, ay0 = 0.f, ax1 = 0.f, ay1 = 0.f;
    float ax2 = 0.f, ay2 = 0.f, ax3 = 0.f, ay3 = 0.f;
    int e = s0;
    for (; e + 3 < s1; e += 4) {
        int2 p0 = esort[e], p1 = esort[e + 1], p2 = esort[e + 2], p3 = esort[e + 3];
        float2 v0 = *(const float2*)(H + (size_t)p0.x * 128 + lane * 2);
        float2 v1 = *(const float2*)(H + (size_t)p1.x * 128 + lane * 2);
        float2 v2 = *(const float2*)(H + (size_t)p2.x * 128 + lane * 2);
        float2 v3 = *(const float2*)(H + (size_t)p3.x * 128 + lane * 2);
        float w0 = __int_as_float(p0.y), w1 = __int_as_float(p1.y);
        float w2 = __int_as_float(p2.y), w3 = __int_as_float(p3.y);
        ax0 += w0 * v0.x; ay0 += w0 * v0.y;
        ax1 += w1 * v1.x; ay1 += w1 * v1.y;
        ax2 += w2 * v2.x; ay2 += w2 * v2.y;
        ax3 += w3 * v3.x; ay3 += w3 * v3.y;
    }
    for (; e < s1; ++e) {
        int2 p0 = esort[e];
        float2 v0 = *(const float2*)(H + (size_t)p0.x * 128 + lane * 2);
        float w0 = __int_as_float(p0.y);
        ax0 += w0 * v0.x; ay0 += w0 * v0.y;
    }
    return make_float2((ax0 + ax1) + (ax2 + ax3), (ay0 + ay1) + (ay2 + ay3));
}

// bias + LayerNorm + relu on a wave-held row (2 dims/lane)
__device__ __forceinline__ float2 ln_relu(float vx, float vy, int lane,
                                          const float* __restrict__ bias,
                                          const float* __restrict__ g,
                                          const float* __restrict__ b) {
    float2 bs = *(const float2*)(bias + lane * 2);
    vx += bs.x; vy += bs.y;
    float s = vx + vy, ss = vx * vx + vy * vy;
    for (int off = 32; off; off >>= 1) {
        s += __shfl_xor(s, off, 64);
        ss += __shfl_xor(ss, off, 64);
    }
    float mu = s * (1.f / 128.f);
    float var = ss * (1.f / 128.f) - mu * mu;
    float rs = rsqrtf(var + 1e-5f);
    float2 gg = *(const float2*)(g + lane * 2);
    float2 bb = *(const float2*)(b + lane * 2);
    return make_float2(fmaxf((vx - mu) * rs * gg.x + bb.x, 0.f),
                       fmaxf((vy - mu) * rs * gg.y + bb.y, 0.f));
}

// ---------------- fused: h1 = relu(LN(agg(bufA)+b)) [kept in LDS]; bufC = h1 @ Wg2^T ----
__global__ __launch_bounds__(256) void agg1_gemm2(const int* __restrict__ row_start,
                                                  const int2* __restrict__ esort,
                                                  const float* __restrict__ bufA,
                                                  const float* __restrict__ Wg2,
                                                  float* __restrict__ bufC,
                                                  const float* __restrict__ bias,
                                                  const float* __restrict__ g,
                                                  const float* __restrict__ b) {
    __shared__ float rows[4 * 128];
    int lane = threadIdx.x & 63, wid = threadIdx.x >> 6;
    int row0 = blockIdx.x * 4;
    {
        float2 a = csr_gather(row_start, esort, bufA, row0 + wid, lane);
        float2 y = ln_relu(a.x, a.y, lane, bias, g, b);
        rows[wid * 128 + lane * 2] = y.x;
        rows[wid * 128 + lane * 2 + 1] = y.y;
    }
    __syncthreads();
    // gemm2: 4x128 @ 128x128^T; W rows streamed from L2 (reused by all blocks)
    int j = threadIdx.x & 127, rh = threadIdx.x >> 7;
    const float4* wp = (const float4*)(Wg2 + (size_t)j * 128);
    const float4* r0 = (const float4*)(rows + rh * 128);
    const float4* r1 = (const float4*)(rows + (rh + 2) * 128);
    float acc0 = 0.f, acc1 = 0.f;
    #pragma unroll 8
    for (int kk = 0; kk < 32; ++kk) {
        float4 w = wp[kk];
        float4 a0 = r0[kk], a1 = r1[kk];
        acc0 += a0.x * w.x + a0.y * w.y + a0.z * w.z + a0.w * w.w;
        acc1 += a1.x * w.x + a1.y * w.y + a1.z * w.z + a1.w * w.w;
    }
    bufC[(size_t)(row0 + rh) * 128 + j] = acc0;
    bufC[(size_t)(row0 + rh + 2) * 128 + j] = acc1;
}

// ---------------- fused: latent = relu(LN(agg(bufC)+b)); pool0 c0; LDS xc0 partials ----
__global__ __launch_bounds__(256) void agg2_pool0(const int* __restrict__ row_start,
                                                  const int2* __restrict__ esort,
                                                  const float* __restrict__ bufC,
                                                  float* __restrict__ latent,
                                                  const float* __restrict__ bias,
                                                  const float* __restrict__ g,
                                                  const float* __restrict__ b,
                                                  const float* __restrict__ p0W,
                                                  const float* __restrict__ p0b,
                                                  const float* __restrict__ gum,
                                                  int* __restrict__ c0,
                                                  float* __restrict__ partials) {
    __shared__ float Ws[1280];
    __shared__ float accs[1280];
    __shared__ float bsh[10];
    for (int i = threadIdx.x; i < 1280; i += 256) { Ws[i] = p0W[i]; accs[i] = 0.f; }
    if (threadIdx.x < 10) bsh[threadIdx.x] = p0b[threadIdx.x];
    __syncthreads();
    int lane = threadIdx.x & 63, wid = threadIdx.x >> 6;
    int base = blockIdx.x * 16;
    for (int rr = 0; rr < 4; ++rr) {
        int row = base + rr * 4 + wid;
        float2 a = csr_gather(row_start, esort, bufC, row, lane);
        float2 y = ln_relu(a.x, a.y, lane, bias, g, b);
        *(float2*)(latent + (size_t)row * 128 + lane * 2) = y;
        float pk[10];
        #pragma unroll
        for (int k = 0; k < 10; ++k)
            pk[k] = y.x * Ws[k * 128 + lane * 2] + y.y * Ws[k * 128 + lane * 2 + 1];
        for (int off = 32; off; off >>= 1) {
            #pragma unroll
            for (int k = 0; k < 10; ++k) pk[k] += __shfl_xor(pk[k], off, 64);
        }
        const float* gr = gum + (size_t)row * 10;
        int best = 0;
        float bv = pk[0] + bsh[0] + gr[0];
        #pragma unroll
        for (int k = 1; k < 10; ++k) {
            float z = pk[k] + bsh[k] + gr[k];
            if (z > bv) { bv = z; best = k; }   // first max wins (jnp.argmax)
        }
        if (lane == 0) c0[row] = best;
        atomicAdd(&accs[best * 128 + lane * 2], y.x);
        atomicAdd(&accs[best * 128 + lane * 2 + 1], y.y);
    }
    __syncthreads();
    for (int i = threadIdx.x; i < 1280; i += 256)
        partials[(size_t)blockIdx.x * 1280 + i] = accs[i];
}

// ---------------- fused: blocks [0,256) A0 edge-pool; blocks [256,266) xc0 reduce ----
__global__ __launch_bounds__(256) void adj_xc0(const int* __restrict__ ei,
                                               const float* __restrict__ ew,
                                               const int* __restrict__ c0,
                                               float* __restrict__ A0,
                                               const float* __restrict__ partials,
                                               float* __restrict__ xc0, int E) {
    if (blockIdx.x < 256) {
        __shared__ float As[100];
        for (int i = threadIdx.x; i < 100; i += 256) As[i] = 0.f;
        __syncthreads();
        for (int e = blockIdx.x * 256 + threadIdx.x; e < E; e += 256 * 256) {
            int a = c0[ei[e]], b = c0[ei[E + e]];
            atomicAdd(&As[a * 10 + b], ew[e]);
        }
        __syncthreads();
        for (int i = threadIdx.x; i < 100; i += 256) atomicAdd(&A0[i], As[i]);
    } else {
        int k = blockIdx.x - 256;
        int d = threadIdx.x & 127, half = threadIdx.x >> 7;
        float s0 = 0.f, s1 = 0.f, s2 = 0.f, s3 = 0.f;
        for (int b = half * 256; b < half * 256 + 256; b += 4) {
            s0 += partials[(size_t)(b    ) * 1280 + k * 128 + d];
            s1 += partials[(size_t)(b + 1) * 1280 + k * 128 + d];
            s2 += partials[(size_t)(b + 2) * 1280 + k * 128 + d];
            s3 += partials[(size_t)(b + 3) * 1280 + k * 128 + d];
        }
        __shared__ float sm[256];
        sm[threadIdx.x] = (s0 + s1) + (s2 + s3);
        __syncthreads();
        if (threadIdx.x < 128) xc0[k * 128 + d] = sm[threadIdx.x] + sm[threadIdx.x + 128];
    }
}

// ---------------- single-block: levels 0/1 coarse math -> tbl[10][16] ----------------
__global__ __launch_bounds__(256) void small_kernel(const float* __restrict__ xc0,
                                                    const float* __restrict__ A0,
                                                    const float* __restrict__ gum1,
                                                    const float* __restrict__ p1W,
                                                    const float* __restrict__ p1b,
                                                    const float* __restrict__ e0W,
                                                    const float* __restrict__ e0b,
                                                    const float* __restrict__ e1W,
                                                    const float* __restrict__ e1b,
                                                    const float* __restrict__ fcW,
                                                    const float* __restrict__ fcb,
                                                    float* __restrict__ tbl) {
    __shared__ float xc0n[10 * 128];
    __shared__ float adj0[100];
    __shared__ float m0[10 * 128];
    __shared__ float l1[10 * 128];
    __shared__ float xc1n[5 * 128];
    __shared__ float l2[5 * 128];
    __shared__ float A1[25];
    __shared__ int c1[10];
    __shared__ float red[4];

    int tid = threadIdx.x;
    int wid = tid >> 6, lane = tid & 63;

    for (int r = wid; r < 10; r += 4) {
        float2 v = *(const float2*)(xc0 + r * 128 + lane * 2);
        float ss = v.x * v.x + v.y * v.y;
        for (int off = 32; off; off >>= 1) ss += __shfl_xor(ss, off, 64);
        float sc = 1.f / fmaxf(sqrtf(ss), 1e-12f);
        xc0n[r * 128 + lane * 2] = v.x * sc;
        xc0n[r * 128 + lane * 2 + 1] = v.y * sc;
    }
    __syncthreads();
    if (tid == 0) {
        float s = 0.f;
        for (int i = 0; i < 100; ++i) s += A0[i];
        red[0] = s + 1e-6f;
    }
    __syncthreads();
    if (tid < 100) adj0[tid] = A0[tid] / red[0];
    __syncthreads();
    for (int idx = tid; idx < 1280; idx += 256) {
        int r = idx >> 7, d = idx & 127;
        float acc = 0.f;
        #pragma unroll
        for (int a = 0; a < 10; ++a) acc += adj0[r * 10 + a] * xc0n[a * 128 + d];
        m0[idx] = acc;
    }
    __syncthreads();
    for (int idx = tid; idx < 1280; idx += 256) {
        int r = idx >> 7, d = idx & 127;
        float acc = e0b[d];
        const float* wrow = e0W + d * 128;
        for (int k = 0; k < 128; ++k) acc += m0[r * 128 + k] * wrow[k];
        l1[idx] = fmaxf(acc, 0.f);
    }
    __syncthreads();
    if (tid < 10) {
        int best = 0;
        float bv = -1e30f;
        for (int j = 0; j < 5; ++j) {
            float acc = p1b[j] + gum1[tid * 5 + j];
            const float* wrow = p1W + j * 128;
            for (int k = 0; k < 128; ++k) acc += l1[tid * 128 + k] * wrow[k];
            if (acc > bv) { bv = acc; best = j; }
        }
        c1[tid] = best;
    }
    __syncthreads();
    for (int idx = tid; idx < 640; idx += 256) {
        int m = idx >> 7, d = idx & 127;
        float acc = 0.f;
        #pragma unroll
        for (int k = 0; k < 10; ++k)
            if (c1[k] == m) acc += l1[k * 128 + d];
        xc1n[idx] = acc;
    }
    __syncthreads();
    for (int r = wid; r < 5; r += 4) {
        float2 v = *(const float2*)(xc1n + r * 128 + lane * 2);
        float ss = v.x * v.x + v.y * v.y;
        for (int off = 32; off; off >>= 1) ss += __shfl_xor(ss, off, 64);
        float sc = 1.f / fmaxf(sqrtf(ss), 1e-12f);
        xc1n[r * 128 + lane * 2] = v.x * sc;
        xc1n[r * 128 + lane * 2 + 1] = v.y * sc;
    }
    __syncthreads();
    if (tid < 25) {
        int m = tid / 5, n = tid % 5;
        float acc = 0.f;
        for (int a = 0; a < 10; ++a)
            for (int b = 0; b < 10; ++b)
                if (c1[a] == m && c1[b] == n) acc += adj0[a * 10 + b];
        A1[tid] = acc;
    }
    __syncthreads();
    if (tid == 0) {
        float s = 0.f;
        for (int i = 0; i < 25; ++i) s += A1[i];
        red[1] = s + 25e-8f;
    }
    __syncthreads();
    float den1 = red[1];
    for (int idx = tid; idx < 640; idx += 256) {
        int r = idx >> 7, d = idx & 127;
        float acc = 0.f;
        #pragma unroll
        for (int a = 0; a < 5; ++a) acc += A1[r * 5 + a] * xc1n[a * 128 + d];
        m0[idx] = acc / den1;
    }
    __syncthreads();
    for (int idx = tid; idx < 640; idx += 256) {
        int r = idx >> 7, d = idx & 127;
        float acc = e1b[d];
        const float* wrow = e1W + d * 128;
        for (int k = 0; k < 128; ++k) acc += m0[r * 128 + k] * wrow[k];
        l2[idx] = fmaxf(acc, 0.f);
    }
    __syncthreads();
    for (int idx = tid; idx < 160; idx += 256) {
        int k = idx >> 4, o = idx & 15;
        float acc = fcb[o];
        const float* fB = fcW + o * 384 + 128;
        const float* fC = fcW + o * 384 + 256;
        const float* a1 = l1 + k * 128;
        const float* a2 = l2 + c1[k] * 128;
        for (int d = 0; d < 128; ++d) acc += a1[d] * fB[d] + a2[d] * fC[d];
        tbl[idx] = acc;
    }
}

// ---------------- out[i] = latent[i] @ fcA^T + tbl[c0[i]], 8-lane groups ----------------
__global__ __launch_bounds__(256) void out_kernel(const float* __restrict__ latent,
                                                  const int* __restrict__ c0,
                                                  const float* __restrict__ tbl,
                                                  const float* __restrict__ fcW,
                                                  float* __restrict__ out) {
    __shared__ float fA[16 * 128];
    __shared__ float ts[160];
    for (int i = threadIdx.x; i < 2048; i += 256) {
        int o = i >> 7, d = i & 127;
        fA[i] = fcW[o * 384 + d];
    }
    for (int i = threadIdx.x; i < 160; i += 256) ts[i] = tbl[i];
    __syncthreads();
    int lane = threadIdx.x & 63;
    int sub = lane & 7;
    int row = blockIdx.x * 32 + (threadIdx.x >> 6) * 8 + (lane >> 3);
    const float4* lp = (const float4*)(latent + (size_t)row * 128 + sub * 16);
    float4 x0 = lp[0], x1 = lp[1], x2 = lp[2], x3 = lp[3];
    float p[16];
    #pragma unroll
    for (int o = 0; o < 16; ++o) {
        const float4* fo = (const float4*)(fA + o * 128 + sub * 16);
        float4 w0 = fo[0], w1 = fo[1], w2 = fo[2], w3 = fo[3];
        float a = x0.x * w0.x + x0.y * w0.y + x0.z * w0.z + x0.w * w0.w;
        a += x1.x * w1.x + x1.y * w1.y + x1.z * w1.z + x1.w * w1.w;
        a += x2.x * w2.x + x2.y * w2.y + x2.z * w2.z + x2.w * w2.w;
        a += x3.x * w3.x + x3.y * w3.y + x3.z * w3.z + x3.w * w3.w;
        p[o] = a;
    }
    #pragma unroll
    for (int off = 1; off < 8; off <<= 1) {
        #pragma unroll
        for (int o = 0; o < 16; ++o) p[o] += __shfl_xor(p[o], off, 64);
    }
    int c = c0[row];
    float2 r = make_float2(p[2 * sub] + ts[c * 16 + 2 * sub],
                           p[2 * sub + 1] + ts[c * 16 + 2 * sub + 1]);
    *(float2*)(out + (size_t)row * 16 + 2 * sub) = r;
}

extern "C" void kernel_launch(void* const* d_in, const int* in_sizes, int n_in,
                              void* d_out, int out_size, void* d_ws, size_t ws_size,
                              hipStream_t stream) {
    const float* x    = (const float*)d_in[0];
    const int*   ei   = (const int*)d_in[1];
    const float* ew   = (const float*)d_in[2];
    const float* g0   = (const float*)d_in[3];
    const float* g1   = (const float*)d_in[4];
    const float* Wg1  = (const float*)d_in[5];
    const float* bg1  = (const float*)d_in[6];
    const float* ln1g = (const float*)d_in[7];
    const float* ln1b = (const float*)d_in[8];
    const float* Wg2  = (const float*)d_in[9];
    const float* bg2  = (const float*)d_in[10];
    const float* ln2g = (const float*)d_in[11];
    const float* ln2b = (const float*)d_in[12];
    const float* p0W  = (const float*)d_in[13];
    const float* p0b  = (const float*)d_in[14];
    const float* p1W  = (const float*)d_in[15];
    const float* p1b  = (const float*)d_in[16];
    const float* e0W  = (const float*)d_in[17];
    const float* e0b  = (const float*)d_in[18];
    const float* e1W  = (const float*)d_in[19];
    const float* e1b  = (const float*)d_in[20];
    const float* fcW  = (const float*)d_in[21];
    const float* fcb  = (const float*)d_in[22];
    float* out = (float*)d_out;

    float* ws   = (float*)d_ws;
    float* bufA = ws;                                        // N*128 f (gemm1 out)
    float* bufB = bufA + (size_t)N_NODES * 128;              // N*128 f (latent)
    float* bufC = bufB + (size_t)N_NODES * 128;              // N*128 f (gemm2 out)
    int*   c0   = (int*)(bufC + (size_t)N_NODES * 128);      // N int
    float* xc0  = (float*)(c0 + N_NODES);                    // 1280 f
    float* tbl  = xc0 + 1280;                                // 160 f
    int*   deg  = (int*)(tbl + 160);                         // 8192 int   <- memset start
    float* A0   = (float*)(deg + N_NODES);                   // 100 f      <- contiguous
    int*   row_start = (int*)(A0 + 100);                     // 8194 int
    int*   cursor    = row_start + N_NODES + 2;              // 8192 int
    int2*  esort     = (int2*)(cursor + N_NODES);            // E int2
    float* partials  = bufA;   // 512*1280 f = 2.6 MB, reuses bufA (dead after agg1_gemm2)

    // zero deg + A0 in one fill
    hipMemsetAsync(deg, 0, (N_NODES + 100) * sizeof(int), stream);

    // layer-1 gemm (agg commutes) fused with dst-histogram
    gemm1_hist<<<N_NODES / 8 + 64, 128, 0, stream>>>(x, Wg1, bufA, ei, deg);
    scan_kernel<<<1, 256, 0, stream>>>(deg, row_start, cursor);
    scatter_kernel<<<N_EDGES / 256, 256, 0, stream>>>(ei, ew, cursor, esort, N_EDGES);

    // agg1 + LN + relu + gemm2 (in-LDS rows) -> bufC
    agg1_gemm2<<<N_NODES / 4, 256, 0, stream>>>(row_start, esort, bufA, Wg2, bufC,
                                                bg1, ln1g, ln1b);

    // agg2 + LN + relu -> latent(bufB), pool0 c0, LDS xc0 partials
    agg2_pool0<<<512, 256, 0, stream>>>(row_start, esort, bufC, bufB,
                                        bg2, ln2g, ln2b, p0W, p0b, g0, c0, partials);

    // A0 edge-pool + xc0 reduce (independent block ranges)
    adj_xc0<<<266, 256, 0, stream>>>(ei, ew, c0, A0, partials, xc0, N_EDGES);

    // coarse levels -> tbl
    small_kernel<<<1, 256, 0, stream>>>(xc0, A0, g1, p1W, p1b, e0W, e0b, e1W, e1b,
                                        fcW, fcb, tbl);

    // final: out = latent @ fcA^T + tbl[c0]
    out_kernel<<<256, 256, 0, stream>>>(bufB, c0, tbl, fcW, out);
}

// Round 9
// 186.104 us; speedup vs baseline: 5.9370x; 1.1173x over previous
//
#include <hip/hip_runtime.h>

#define N_NODES 8192
#define N_EDGES 262144
#define NFEAT 200
#define NHID 128

// ---------------- GEMM body: C[8 rows,128] = A[8,K] @ W[128,K]^T ----------------
template<int K>
__device__ __forceinline__ void gemm_body(const float* __restrict__ A,
                                          const float* __restrict__ W,
                                          float* __restrict__ C, int bid) {
    __shared__ float a_s[8 * K];
    int row0 = bid * 8;
    const float* Ab = A + (size_t)row0 * K;
    for (int idx = threadIdx.x; idx < 8 * K; idx += 128) a_s[idx] = Ab[idx];
    __syncthreads();
    int j = threadIdx.x;
    float acc[8] = {0.f, 0.f, 0.f, 0.f, 0.f, 0.f, 0.f, 0.f};
    const float4* W4 = (const float4*)(W + (size_t)j * K);
    for (int k4 = 0; k4 < K / 4; ++k4) {
        float4 w = W4[k4];
        int k = k4 * 4;
        #pragma unroll
        for (int r = 0; r < 8; ++r) {
            const float* ar = a_s + r * K + k;
            acc[r] += ar[0] * w.x + ar[1] * w.y + ar[2] * w.z + ar[3] * w.w;
        }
    }
    #pragma unroll
    for (int r = 0; r < 8; ++r) C[(size_t)(row0 + r) * 128 + j] = acc[r];
}

template<int K>
__global__ __launch_bounds__(128) void gemm_rows(const float* __restrict__ A,
                                                 const float* __restrict__ W,
                                                 float* __restrict__ C) {
    gemm_body<K>(A, W, C, blockIdx.x);
}

// fused: blocks [0,1024) gemm layer-1; blocks [1024,1088) histogram of dst
__global__ __launch_bounds__(128) void gemm1_hist(const float* __restrict__ A,
                                                  const float* __restrict__ W,
                                                  float* __restrict__ C,
                                                  const int* __restrict__ ei,
                                                  int* __restrict__ deg) {
    if (blockIdx.x < N_NODES / 8) {
        gemm_body<NFEAT>(A, W, C, blockIdx.x);
    } else {
        const int* dst = ei + N_EDGES;
        for (int e = (blockIdx.x - N_NODES / 8) * 128 + threadIdx.x; e < N_EDGES; e += 64 * 128)
            atomicAdd(&deg[dst[e]], 1);
    }
}

// single block, 256 threads: exclusive prefix sum of deg[8192] -> row_start, cursor
__global__ __launch_bounds__(256) void scan_kernel(const int* __restrict__ deg,
                                                   int* __restrict__ row_start,
                                                   int* __restrict__ cursor) {
    __shared__ int part[256];
    __shared__ int partx[257];
    int tid = threadIdx.x;
    int base = tid * 32;
    int s = 0;
    for (int i = 0; i < 32; ++i) s += deg[base + i];
    part[tid] = s;
    __syncthreads();
    if (tid == 0) {
        int run = 0;
        for (int i = 0; i < 256; ++i) { partx[i] = run; run += part[i]; }
        partx[256] = run;
    }
    __syncthreads();
    int run = partx[tid];
    for (int i = 0; i < 32; ++i) {
        row_start[base + i] = run;
        cursor[base + i] = run;
        run += deg[base + i];
    }
    if (tid == 255) row_start[N_NODES] = run;
}

// scatter edges into dst-sorted order, packed (src, weight-bits)
__global__ __launch_bounds__(256) void scatter_kernel(const int* __restrict__ ei,
                                                      const float* __restrict__ ew,
                                                      int* __restrict__ cursor,
                                                      int2* __restrict__ esort, int E) {
    int e = blockIdx.x * blockDim.x + threadIdx.x;
    if (e < E) {
        int d = ei[E + e];
        int pos = atomicAdd(&cursor[d], 1);
        esort[pos] = make_int2(ei[e], __float_as_int(ew[e]));
    }
}

// weighted CSR gather, lane-parallel edge prefetch + shuffle broadcast:
// one coalesced esort load covers 64 edges; H loads then issue back-to-back.
__device__ __forceinline__ float2 csr_gather(const int* __restrict__ row_start,
                                             const int2* __restrict__ esort,
                                             const float* __restrict__ H,
                                             int row, int lane) {
    int s0 = row_start[row], s1 = row_start[row + 1];
    float ax0 = 0.f, ay0 = 0.f, ax1 = 0.f, ay1 = 0.f;
    float ax2 = 0.f, ay2 = 0.f, ax3 = 0.f, ay3 = 0.f;
    for (int base = s0; base < s1; base += 64) {
        int n = s1 - base;
        if (n > 64) n = 64;
        int2 meta = make_int2(0, 0);
        if (lane < n) meta = esort[base + lane];
        int k = 0;
        for (; k + 3 < n; k += 4) {
            int sA = __shfl(meta.x, k, 64);
            int sB = __shfl(meta.x, k + 1, 64);
            int sC = __shfl(meta.x, k + 2, 64);
            int sD = __shfl(meta.x, k + 3, 64);
            float wA = __int_as_float(__shfl(meta.y, k, 64));
            float wB = __int_as_float(__shfl(meta.y, k + 1, 64));
            float wC = __int_as_float(__shfl(meta.y, k + 2, 64));
            float wD = __int_as_float(__shfl(meta.y, k + 3, 64));
            float2 vA = *(const float2*)(H + (size_t)sA * 128 + lane * 2);
            float2 vB = *(const float2*)(H + (size_t)sB * 128 + lane * 2);
            float2 vC = *(const float2*)(H + (size_t)sC * 128 + lane * 2);
            float2 vD = *(const float2*)(H + (size_t)sD * 128 + lane * 2);
            ax0 += wA * vA.x; ay0 += wA * vA.y;
            ax1 += wB * vB.x; ay1 += wB * vB.y;
            ax2 += wC * vC.x; ay2 += wC * vC.y;
            ax3 += wD * vD.x; ay3 += wD * vD.y;
        }
        for (; k < n; ++k) {
            int sA = __shfl(meta.x, k, 64);
            float wA = __int_as_float(__shfl(meta.y, k, 64));
            float2 vA = *(const float2*)(H + (size_t)sA * 128 + lane * 2);
            ax0 += wA * vA.x; ay0 += wA * vA.y;
        }
    }
    return make_float2((ax0 + ax1) + (ax2 + ax3), (ay0 + ay1) + (ay2 + ay3));
}

// bias + LayerNorm + relu on a wave-held row (2 dims/lane)
__device__ __forceinline__ float2 ln_relu(float vx, float vy, int lane,
                                          const float* __restrict__ bias,
                                          const float* __restrict__ g,
                                          const float* __restrict__ b) {
    float2 bs = *(const float2*)(bias + lane * 2);
    vx += bs.x; vy += bs.y;
    float s = vx + vy, ss = vx * vx + vy * vy;
    for (int off = 32; off; off >>= 1) {
        s += __shfl_xor(s, off, 64);
        ss += __shfl_xor(ss, off, 64);
    }
    float mu = s * (1.f / 128.f);
    float var = ss * (1.f / 128.f) - mu * mu;
    float rs = rsqrtf(var + 1e-5f);
    float2 gg = *(const float2*)(g + lane * 2);
    float2 bb = *(const float2*)(b + lane * 2);
    return make_float2(fmaxf((vx - mu) * rs * gg.x + bb.x, 0.f),
                       fmaxf((vy - mu) * rs * gg.y + bb.y, 0.f));
}

// ---------------- out[i] = relu(LN(agg(H)+bias)), one wave per row ----------------
__global__ __launch_bounds__(256) void agg_ln_csr(const int* __restrict__ row_start,
                                                  const int2* __restrict__ esort,
                                                  const float* __restrict__ H,
                                                  float* __restrict__ out,
                                                  const float* __restrict__ bias,
                                                  const float* __restrict__ g,
                                                  const float* __restrict__ b) {
    int wave = (blockIdx.x * blockDim.x + threadIdx.x) >> 6;
    int lane = threadIdx.x & 63;
    float2 a = csr_gather(row_start, esort, H, wave, lane);
    float2 y = ln_relu(a.x, a.y, lane, bias, g, b);
    *(float2*)(out + (size_t)wave * 128 + lane * 2) = y;
}

// ---------------- fused: latent = relu(LN(agg(bufC)+b)); pool0 c0; LDS xc0 partials ----
__global__ __launch_bounds__(256) void agg2_pool0(const int* __restrict__ row_start,
                                                  const int2* __restrict__ esort,
                                                  const float* __restrict__ bufC,
                                                  float* __restrict__ latent,
                                                  const float* __restrict__ bias,
                                                  const float* __restrict__ g,
                                                  const float* __restrict__ b,
                                                  const float* __restrict__ p0W,
                                                  const float* __restrict__ p0b,
                                                  const float* __restrict__ gum,
                                                  int* __restrict__ c0,
                                                  float* __restrict__ partials) {
    __shared__ float Ws[1280];
    __shared__ float accs[1280];
    __shared__ float bsh[10];
    for (int i = threadIdx.x; i < 1280; i += 256) { Ws[i] = p0W[i]; accs[i] = 0.f; }
    if (threadIdx.x < 10) bsh[threadIdx.x] = p0b[threadIdx.x];
    __syncthreads();
    int lane = threadIdx.x & 63, wid = threadIdx.x >> 6;
    int base = blockIdx.x * 16;
    for (int rr = 0; rr < 4; ++rr) {
        int row = base + rr * 4 + wid;
        float2 a = csr_gather(row_start, esort, bufC, row, lane);
        float2 y = ln_relu(a.x, a.y, lane, bias, g, b);
        *(float2*)(latent + (size_t)row * 128 + lane * 2) = y;
        float pk[10];
        #pragma unroll
        for (int k = 0; k < 10; ++k)
            pk[k] = y.x * Ws[k * 128 + lane * 2] + y.y * Ws[k * 128 + lane * 2 + 1];
        for (int off = 32; off; off >>= 1) {
            #pragma unroll
            for (int k = 0; k < 10; ++k) pk[k] += __shfl_xor(pk[k], off, 64);
        }
        const float* gr = gum + (size_t)row * 10;
        int best = 0;
        float bv = pk[0] + bsh[0] + gr[0];
        #pragma unroll
        for (int k = 1; k < 10; ++k) {
            float z = pk[k] + bsh[k] + gr[k];
            if (z > bv) { bv = z; best = k; }   // first max wins (jnp.argmax)
        }
        if (lane == 0) c0[row] = best;
        atomicAdd(&accs[best * 128 + lane * 2], y.x);
        atomicAdd(&accs[best * 128 + lane * 2 + 1], y.y);
    }
    __syncthreads();
    for (int i = threadIdx.x; i < 1280; i += 256)
        partials[(size_t)blockIdx.x * 1280 + i] = accs[i];
}

// ---------------- fused: blocks [0,256) A0 edge-pool; blocks [256,266) xc0 reduce ----
__global__ __launch_bounds__(256) void adj_xc0(const int* __restrict__ ei,
                                               const float* __restrict__ ew,
                                               const int* __restrict__ c0,
                                               float* __restrict__ A0,
                                               const float* __restrict__ partials,
                                               float* __restrict__ xc0, int E) {
    if (blockIdx.x < 256) {
        __shared__ float As[100];
        for (int i = threadIdx.x; i < 100; i += 256) As[i] = 0.f;
        __syncthreads();
        for (int e = blockIdx.x * 256 + threadIdx.x; e < E; e += 256 * 256) {
            int a = c0[ei[e]], b = c0[ei[E + e]];
            atomicAdd(&As[a * 10 + b], ew[e]);
        }
        __syncthreads();
        for (int i = threadIdx.x; i < 100; i += 256) atomicAdd(&A0[i], As[i]);
    } else {
        int k = blockIdx.x - 256;
        int d = threadIdx.x & 127, half = threadIdx.x >> 7;
        float s0 = 0.f, s1 = 0.f, s2 = 0.f, s3 = 0.f;
        for (int b = half * 256; b < half * 256 + 256; b += 4) {
            s0 += partials[(size_t)(b    ) * 1280 + k * 128 + d];
            s1 += partials[(size_t)(b + 1) * 1280 + k * 128 + d];
            s2 += partials[(size_t)(b + 2) * 1280 + k * 128 + d];
            s3 += partials[(size_t)(b + 3) * 1280 + k * 128 + d];
        }
        __shared__ float sm[256];
        sm[threadIdx.x] = (s0 + s1) + (s2 + s3);
        __syncthreads();
        if (threadIdx.x < 128) xc0[k * 128 + d] = sm[threadIdx.x] + sm[threadIdx.x + 128];
    }
}

// ---------------- single-block: levels 0/1 coarse math -> tbl[10][16] ----------------
__global__ __launch_bounds__(256) void small_kernel(const float* __restrict__ xc0,
                                                    const float* __restrict__ A0,
                                                    const float* __restrict__ gum1,
                                                    const float* __restrict__ p1W,
                                                    const float* __restrict__ p1b,
                                                    const float* __restrict__ e0W,
                                                    const float* __restrict__ e0b,
                                                    const float* __restrict__ e1W,
                                                    const float* __restrict__ e1b,
                                                    const float* __restrict__ fcW,
                                                    const float* __restrict__ fcb,
                                                    float* __restrict__ tbl) {
    __shared__ float xc0n[10 * 128];
    __shared__ float adj0[100];
    __shared__ float m0[10 * 128];
    __shared__ float l1[10 * 128];
    __shared__ float xc1n[5 * 128];
    __shared__ float l2[5 * 128];
    __shared__ float A1[25];
    __shared__ int c1[10];
    __shared__ float red[4];

    int tid = threadIdx.x;
    int wid = tid >> 6, lane = tid & 63;

    for (int r = wid; r < 10; r += 4) {
        float2 v = *(const float2*)(xc0 + r * 128 + lane * 2);
        float ss = v.x * v.x + v.y * v.y;
        for (int off = 32; off; off >>= 1) ss += __shfl_xor(ss, off, 64);
        float sc = 1.f / fmaxf(sqrtf(ss), 1e-12f);
        xc0n[r * 128 + lane * 2] = v.x * sc;
        xc0n[r * 128 + lane * 2 + 1] = v.y * sc;
    }
    __syncthreads();
    if (tid == 0) {
        float s = 0.f;
        for (int i = 0; i < 100; ++i) s += A0[i];
        red[0] = s + 1e-6f;
    }
    __syncthreads();
    if (tid < 100) adj0[tid] = A0[tid] / red[0];
    __syncthreads();
    for (int idx = tid; idx < 1280; idx += 256) {
        int r = idx >> 7, d = idx & 127;
        float acc = 0.f;
        #pragma unroll
        for (int a = 0; a < 10; ++a) acc += adj0[r * 10 + a] * xc0n[a * 128 + d];
        m0[idx] = acc;
    }
    __syncthreads();
    for (int idx = tid; idx < 1280; idx += 256) {
        int r = idx >> 7, d = idx & 127;
        float acc = e0b[d];
        const float* wrow = e0W + d * 128;
        for (int k = 0; k < 128; ++k) acc += m0[r * 128 + k] * wrow[k];
        l1[idx] = fmaxf(acc, 0.f);
    }
    __syncthreads();
    if (tid < 10) {
        int best = 0;
        float bv = -1e30f;
        for (int j = 0; j < 5; ++j) {
            float acc = p1b[j] + gum1[tid * 5 + j];
            const float* wrow = p1W + j * 128;
            for (int k = 0; k < 128; ++k) acc += l1[tid * 128 + k] * wrow[k];
            if (acc > bv) { bv = acc; best = j; }
        }
        c1[tid] = best;
    }
    __syncthreads();
    for (int idx = tid; idx < 640; idx += 256) {
        int m = idx >> 7, d = idx & 127;
        float acc = 0.f;
        #pragma unroll
        for (int k = 0; k < 10; ++k)
            if (c1[k] == m) acc += l1[k * 128 + d];
        xc1n[idx] = acc;
    }
    __syncthreads();
    for (int r = wid; r < 5; r += 4) {
        float2 v = *(const float2*)(xc1n + r * 128 + lane * 2);
        float ss = v.x * v.x + v.y * v.y;
        for (int off = 32; off; off >>= 1) ss += __shfl_xor(ss, off, 64);
        float sc = 1.f / fmaxf(sqrtf(ss), 1e-12f);
        xc1n[r * 128 + lane * 2] = v.x * sc;
        xc1n[r * 128 + lane * 2 + 1] = v.y * sc;
    }
    __syncthreads();
    if (tid < 25) {
        int m = tid / 5, n = tid % 5;
        float acc = 0.f;
        for (int a = 0; a < 10; ++a)
            for (int b = 0; b < 10; ++b)
                if (c1[a] == m && c1[b] == n) acc += adj0[a * 10 + b];
        A1[tid] = acc;
    }
    __syncthreads();
    if (tid == 0) {
        float s = 0.f;
        for (int i = 0; i < 25; ++i) s += A1[i];
        red[1] = s + 25e-8f;
    }
    __syncthreads();
    float den1 = red[1];
    for (int idx = tid; idx < 640; idx += 256) {
        int r = idx >> 7, d = idx & 127;
        float acc = 0.f;
        #pragma unroll
        for (int a = 0; a < 5; ++a) acc += A1[r * 5 + a] * xc1n[a * 128 + d];
        m0[idx] = acc / den1;
    }
    __syncthreads();
    for (int idx = tid; idx < 640; idx += 256) {
        int r = idx >> 7, d = idx & 127;
        float acc = e1b[d];
        const float* wrow = e1W + d * 128;
        for (int k = 0; k < 128; ++k) acc += m0[r * 128 + k] * wrow[k];
        l2[idx] = fmaxf(acc, 0.f);
    }
    __syncthreads();
    for (int idx = tid; idx < 160; idx += 256) {
        int k = idx >> 4, o = idx & 15;
        float acc = fcb[o];
        const float* fB = fcW + o * 384 + 128;
        const float* fC = fcW + o * 384 + 256;
        const float* a1 = l1 + k * 128;
        const float* a2 = l2 + c1[k] * 128;
        for (int d = 0; d < 128; ++d) acc += a1[d] * fB[d] + a2[d] * fC[d];
        tbl[idx] = acc;
    }
}

// ---------------- out[i] = latent[i] @ fcA^T + tbl[c0[i]], 8-lane groups ----------------
__global__ __launch_bounds__(256) void out_kernel(const float* __restrict__ latent,
                                                  const int* __restrict__ c0,
                                                  const float* __restrict__ tbl,
                                                  const float* __restrict__ fcW,
                                                  float* __restrict__ out) {
    __shared__ float fA[16 * 128];
    __shared__ float ts[160];
    for (int i = threadIdx.x; i < 2048; i += 256) {
        int o = i >> 7, d = i & 127;
        fA[i] = fcW[o * 384 + d];
    }
    for (int i = threadIdx.x; i < 160; i += 256) ts[i] = tbl[i];
    __syncthreads();
    int lane = threadIdx.x & 63;
    int sub = lane & 7;
    int row = blockIdx.x * 32 + (threadIdx.x >> 6) * 8 + (lane >> 3);
    const float4* lp = (const float4*)(latent + (size_t)row * 128 + sub * 16);
    float4 x0 = lp[0], x1 = lp[1], x2 = lp[2], x3 = lp[3];
    float p[16];
    #pragma unroll
    for (int o = 0; o < 16; ++o) {
        const float4* fo = (const float4*)(fA + o * 128 + sub * 16);
        float4 w0 = fo[0], w1 = fo[1], w2 = fo[2], w3 = fo[3];
        float a = x0.x * w0.x + x0.y * w0.y + x0.z * w0.z + x0.w * w0.w;
        a += x1.x * w1.x + x1.y * w1.y + x1.z * w1.z + x1.w * w1.w;
        a += x2.x * w2.x + x2.y * w2.y + x2.z * w2.z + x2.w * w2.w;
        a += x3.x * w3.x + x3.y * w3.y + x3.z * w3.z + x3.w * w3.w;
        p[o] = a;
    }
    #pragma unroll
    for (int off = 1; off < 8; off <<= 1) {
        #pragma unroll
        for (int o = 0; o < 16; ++o) p[o] += __shfl_xor(p[o], off, 64);
    }
    int c = c0[row];
    float2 r = make_float2(p[2 * sub] + ts[c * 16 + 2 * sub],
                           p[2 * sub + 1] + ts[c * 16 + 2 * sub + 1]);
    *(float2*)(out + (size_t)row * 16 + 2 * sub) = r;
}

extern "C" void kernel_launch(void* const* d_in, const int* in_sizes, int n_in,
                              void* d_out, int out_size, void* d_ws, size_t ws_size,
                              hipStream_t stream) {
    const float* x    = (const float*)d_in[0];
    const int*   ei   = (const int*)d_in[1];
    const float* ew   = (const float*)d_in[2];
    const float* g0   = (const float*)d_in[3];
    const float* g1   = (const float*)d_in[4];
    const float* Wg1  = (const float*)d_in[5];
    const float* bg1  = (const float*)d_in[6];
    const float* ln1g = (const float*)d_in[7];
    const float* ln1b = (const float*)d_in[8];
    const float* Wg2  = (const float*)d_in[9];
    const float* bg2  = (const float*)d_in[10];
    const float* ln2g = (const float*)d_in[11];
    const float* ln2b = (const float*)d_in[12];
    const float* p0W  = (const float*)d_in[13];
    const float* p0b  = (const float*)d_in[14];
    const float* p1W  = (const float*)d_in[15];
    const float* p1b  = (const float*)d_in[16];
    const float* e0W  = (const float*)d_in[17];
    const float* e0b  = (const float*)d_in[18];
    const float* e1W  = (const float*)d_in[19];
    const float* e1b  = (const float*)d_in[20];
    const float* fcW  = (const float*)d_in[21];
    const float* fcb  = (const float*)d_in[22];
    float* out = (float*)d_out;

    float* ws   = (float*)d_ws;
    float* bufA = ws;                                        // N*128 f (gemm1 out)
    float* bufB = bufA + (size_t)N_NODES * 128;              // N*128 f (latent / h1)
    float* bufC = bufB + (size_t)N_NODES * 128;              // N*128 f (gemm2 out)
    int*   c0   = (int*)(bufC + (size_t)N_NODES * 128);      // N int
    float* xc0  = (float*)(c0 + N_NODES);                    // 1280 f
    float* tbl  = xc0 + 1280;                                // 160 f
    int*   deg  = (int*)(tbl + 160);                         // 8192 int   <- memset start
    float* A0   = (float*)(deg + N_NODES);                   // 100 f      <- contiguous
    int*   row_start = (int*)(A0 + 100);                     // 8194 int
    int*   cursor    = row_start + N_NODES + 2;              // 8192 int
    int2*  esort     = (int2*)(cursor + N_NODES);            // E int2
    float* partials  = bufA;   // 512*1280 f = 2.6 MB, reuses bufA (dead after gemm2)

    // zero deg + A0 in one fill
    hipMemsetAsync(deg, 0, (N_NODES + 100) * sizeof(int), stream);

    // layer-1 gemm (agg commutes) fused with dst-histogram
    gemm1_hist<<<N_NODES / 8 + 64, 128, 0, stream>>>(x, Wg1, bufA, ei, deg);
    scan_kernel<<<1, 256, 0, stream>>>(deg, row_start, cursor);
    scatter_kernel<<<N_EDGES / 256, 256, 0, stream>>>(ei, ew, cursor, esort, N_EDGES);

    // agg1 + LN + relu -> bufB (h1)
    agg_ln_csr<<<N_NODES / 4, 256, 0, stream>>>(row_start, esort, bufA, bufB,
                                                bg1, ln1g, ln1b);
    // gemm2: bufC = h1 @ Wg2^T
    gemm_rows<NHID><<<N_NODES / 8, 128, 0, stream>>>(bufB, Wg2, bufC);

    // agg2 + LN + relu -> latent(bufB), pool0 c0, LDS xc0 partials
    agg2_pool0<<<512, 256, 0, stream>>>(row_start, esort, bufC, bufB,
                                        bg2, ln2g, ln2b, p0W, p0b, g0, c0, partials);

    // A0 edge-pool + xc0 reduce (independent block ranges)
    adj_xc0<<<266, 256, 0, stream>>>(ei, ew, c0, A0, partials, xc0, N_EDGES);

    // coarse levels -> tbl
    small_kernel<<<1, 256, 0, stream>>>(xc0, A0, g1, p1W, p1b, e0W, e0b, e1W, e1b,
                                        fcW, fcb, tbl);

    // final: out = latent @ fcA^T + tbl[c0]
    out_kernel<<<256, 256, 0, stream>>>(bufB, c0, tbl, fcW, out);
}